// Round 6
// baseline (266.167 us; speedup 1.0000x reference)
//
#include <hip/hip_runtime.h>

// ExpandEvecs: out[b][k][n][m] = sum_{j<=k} e[b][n][j] * e[b][m][j]
// B=4, C=1, N=1024, K=16. fp32 in / fp32 out. Output 268.4 MB.
// dur_us = harness re-poison fill (~162 us, always the top-5 rows) + kernel.
// Kernel ~95 us across R4/R6/R7/R9 vs ~41 us fill-rate floor (2.8 vs 6.6 TB/s).
//
// Falsified limiters: store fencing (R6/R7), store address pattern (R6 vs
// R7), load divergence (R6 transpose), cache write-allocate (R9 nt: null).
// Remaining theory (R10): the fill hits 6.6 TB/s at ~10% occupancy with
// few LONG-LIVED waves streaming stores continuously; all our kernels had
// short-burst or fenced store streams from churning waves -> low
// time-averaged bytes-in-flight. R10 mimics the fill:
//   * 512 blocks = exactly 2/CU, one generation, waves live whole kernel.
//   * thread: em[16] resident (4 m-cols x all k), loop 8 n-rows with TWO
//     rotating prefix instances vA/vB (independent regs). compute A ->
//     16 nt stores A -> compute B (overlaps A's store consumption) ->
//     16 nt stores B -> ... : 128 stores/thread spread over wave life,
//     always ~16 stores in flight, no fence ever drains to zero.
//   * cumsum form: 4 FMA per stored float4 (minimal VALU).

#define BB 4
#define NN 1024
#define KK 16
#define RPB 8                  // n-rows per block
#define NGRP (NN / RPB)        // 128 row-groups per batch

typedef float f32x4 __attribute__((ext_vector_type(4)));

__global__ __launch_bounds__(256) void ExpandEvecs_75780402970966_evT(
    const float* __restrict__ ev,   // [B][N][K]
    float* __restrict__ evT)        // [B][K][N]
{
    const int b  = blockIdx.x >> 2;
    const int mc = blockIdx.x & 3;
    const int m  = mc * 256 + threadIdx.x;
    const float* src = ev + (size_t)(b * NN + m) * KK;
    float* dst = evT + (size_t)b * KK * NN + m;
#pragma unroll
    for (int k = 0; k < KK; ++k)
        dst[(size_t)k * NN] = src[k];   // coalesced stores, tiny gather reads
}

__global__ __launch_bounds__(256, 2) void ExpandEvecs_75780402970966_kernel(
    const float* __restrict__ ev,   // [B][N][K] (uniform n-row reads)
    const float* __restrict__ evT,  // [B][K][N] (workspace, coalesced)
    float* __restrict__ out)        // [B][K][N][N]
{
    const int tid = threadIdx.x;
    const int m0  = tid << 2;                 // 256 threads x 4 m = all m
    const int ng  = blockIdx.x & (NGRP - 1);
    const int b   = blockIdx.x >> 7;
    const int n0  = ng * RPB;

    const float* __restrict__ eb = ev  + (size_t)b * NN * KK;
    const float* __restrict__ eT = evT + (size_t)b * KK * NN + m0;

    // em[k] = evT[b][k][m0..m0+3] — resident for the whole wave (64 VGPR).
    f32x4 em[KK];
#pragma unroll
    for (int k = 0; k < KK; ++k)
        em[k] = *(const f32x4*)(eT + (size_t)k * NN);

    const size_t kplane = (size_t)NN * NN;
    float* ob0 = out + (size_t)b * KK * kplane + (size_t)n0 * NN + m0;

    // Rolled row loop: two independent prefix instances per iteration.
    for (int nr = 0; nr < RPB; nr += 2) {
        // ---- row A = n0+nr ----
        const float* __restrict__ enA = eb + (size_t)(n0 + nr) * KK;  // uniform
        f32x4 vA[KK];
        vA[0] = em[0] * enA[0];
#pragma unroll
        for (int k = 1; k < KK; ++k) {
            const float e = enA[k];
            vA[k].x = fmaf(em[k].x, e, vA[k - 1].x);
            vA[k].y = fmaf(em[k].y, e, vA[k - 1].y);
            vA[k].z = fmaf(em[k].z, e, vA[k - 1].z);
            vA[k].w = fmaf(em[k].w, e, vA[k - 1].w);
        }
        float* obA = ob0 + (size_t)nr * NN;
#pragma unroll
        for (int k = 0; k < KK; ++k)
            __builtin_nontemporal_store(vA[k], (f32x4*)(obA + (size_t)k * kplane));

        // ---- row B = n0+nr+1 (independent regs; FMAs overlap A's stores) ----
        const float* __restrict__ enB = eb + (size_t)(n0 + nr + 1) * KK;
        f32x4 vB[KK];
        vB[0] = em[0] * enB[0];
#pragma unroll
        for (int k = 1; k < KK; ++k) {
            const float e = enB[k];
            vB[k].x = fmaf(em[k].x, e, vB[k - 1].x);
            vB[k].y = fmaf(em[k].y, e, vB[k - 1].y);
            vB[k].z = fmaf(em[k].z, e, vB[k - 1].z);
            vB[k].w = fmaf(em[k].w, e, vB[k - 1].w);
        }
        float* obB = ob0 + (size_t)(nr + 1) * NN;
#pragma unroll
        for (int k = 0; k < KK; ++k)
            __builtin_nontemporal_store(vB[k], (f32x4*)(obB + (size_t)k * kplane));
    }
}

// Fallback (no workspace): one block per (b,n) row, reads ev directly with
// in-register component select. Correctness only.
__global__ __launch_bounds__(256) void ExpandEvecs_75780402970966_fallback(
    const float* __restrict__ ev, float* __restrict__ out)
{
    const int tid = threadIdx.x;
    const int m0  = tid << 2;
    const int n   = blockIdx.x & (NN - 1);
    const int b   = blockIdx.x >> 10;
    const float* __restrict__ en = ev + (size_t)(b * NN + n) * KK;

    float4 f[16];
    const float* base = ev + ((size_t)b * NN + m0) * KK;
#pragma unroll
    for (int i = 0; i < 16; ++i)
        f[i] = *(const float4*)(base + i * 4);

    f32x4 v[KK];
#pragma unroll
    for (int k = 0; k < KK; ++k) {
        f32x4 t;
        t.x = ((const float*)&f[0  + (k >> 2)])[k & 3];
        t.y = ((const float*)&f[4  + (k >> 2)])[k & 3];
        t.z = ((const float*)&f[8  + (k >> 2)])[k & 3];
        t.w = ((const float*)&f[12 + (k >> 2)])[k & 3];
        v[k] = t;
    }
    v[0] *= en[0];
#pragma unroll
    for (int k = 1; k < KK; ++k) {
        const float ek = en[k];
        v[k].x = fmaf(v[k].x, ek, v[k - 1].x);
        v[k].y = fmaf(v[k].y, ek, v[k - 1].y);
        v[k].z = fmaf(v[k].z, ek, v[k - 1].z);
        v[k].w = fmaf(v[k].w, ek, v[k - 1].w);
    }
    const size_t kplane = (size_t)NN * NN;
    float* ob = out + (size_t)b * KK * kplane + (size_t)n * NN + m0;
#pragma unroll
    for (int k = 0; k < KK; ++k)
        __builtin_nontemporal_store(v[k], (f32x4*)(ob + (size_t)k * kplane));
}

extern "C" void kernel_launch(void* const* d_in, const int* in_sizes, int n_in,
                              void* d_out, int out_size, void* d_ws, size_t ws_size,
                              hipStream_t stream) {
    const float* ev = (const float*)d_in[0];
    float* out = (float*)d_out;

    const size_t evT_bytes = (size_t)BB * KK * NN * sizeof(float);  // 256 KB
    if (ws_size >= evT_bytes && d_ws != nullptr) {
        float* evT = (float*)d_ws;
        ExpandEvecs_75780402970966_evT<<<BB * 4, 256, 0, stream>>>(ev, evT);
        ExpandEvecs_75780402970966_kernel
            <<<BB * NGRP, 256, 0, stream>>>(ev, evT, out);
    } else {
        ExpandEvecs_75780402970966_fallback
            <<<BB * NN, 256, 0, stream>>>(ev, out);
    }
}

// Round 7
// 257.739 us; speedup vs baseline: 1.0327x; 1.0327x over previous
//
#include <hip/hip_runtime.h>

// ExpandEvecs: out[b][k][n][m] = sum_{j<=k} e[b][n][j] * e[b][m][j]
// B=4, C=1, N=1024, K=16. fp32 in / fp32 out. Output 268.4 MB.
//
// FINAL (revert to best-known R4 structure, single launch).
// Session findings: dur_us = harness re-poison fill (~162-172 us; always the
// only top-5 rocprof rows, 1.07 GB @ 6.6 TB/s) + our kernel. Six kernel
// structures measured: fenced cumsum (94 us), k-parallel recompute w/
// gathers (170), transpose+unfenced burst (102), transpose+linear sweep
// (96), +nontemporal (103), 2blk/CU streaming waves (104). Every
// compute-sourced structure equilibrates at ~2.85 TB/s write vs the fill's
// 6.6 TB/s with PLAIN stores -- so no store flag/pattern/fencing/occupancy
// theory survives. Residual gap attributed to harness-environment effects
// (L3 dirty-residue drain from the 1.07 GB poison charged to our window +
// graph node serialization), not kernel source. R4 single-launch is the
// floor of the band: no pre-kernel launch cost, contiguous-per-thread
// 256 B em loads (wave-coalesced), block-uniform en s_loads, 32 KiB
// contiguous stores per block per k-step.

#define BB 4
#define NN 1024
#define KK 16
#define ROWS 8

__global__ __launch_bounds__(256) void ExpandEvecs_75780402970966_kernel(
    const float* __restrict__ ev,   // [B][N][K] float32
    float* __restrict__ out)        // [B][K][N][N] float32
{
    const int tid = threadIdx.x;
    const int m0  = tid << 2;                 // 256 threads x 4 m = all 1024 m
    const int grp = blockIdx.x & 127;         // n-group within b
    const int b   = blockIdx.x >> 7;
    const int n0  = grp * ROWS;

    const float* eb = ev + (size_t)b * NN * KK;   // this batch's slab (64 KiB)

    float acc[ROWS][4];
#pragma unroll
    for (int r = 0; r < ROWS; ++r)
#pragma unroll
        for (int v = 0; v < 4; ++v) acc[r][v] = 0.0f;

    const size_t kplane = (size_t)NN * NN;
    const size_t obase  = (size_t)b * KK * kplane + (size_t)n0 * NN + (size_t)m0;

#pragma unroll
    for (int kb = 0; kb < KK / 4; ++kb) {          // k in blocks of 4
        float4 em4[4];                              // this thread's 4 m-rows
#pragma unroll
        for (int v = 0; v < 4; ++v)
            em4[v] = *(const float4*)(eb + (size_t)(m0 + v) * KK + kb * 4);

        float4 en4[ROWS];                           // block-uniform -> s_load
#pragma unroll
        for (int r = 0; r < ROWS; ++r)
            en4[r] = *(const float4*)(eb + (size_t)(n0 + r) * KK + kb * 4);

#pragma unroll
        for (int kk = 0; kk < 4; ++kk) {
            const int k = kb * 4 + kk;
            float* outk = out + obase + (size_t)k * kplane;
#pragma unroll
            for (int r = 0; r < ROWS; ++r) {
                const float enk = ((const float*)&en4[r])[kk];
#pragma unroll
                for (int v = 0; v < 4; ++v)
                    acc[r][v] = fmaf(((const float*)&em4[v])[kk], enk, acc[r][v]);
                *(float4*)(outk + (size_t)r * NN) =
                    make_float4(acc[r][0], acc[r][1], acc[r][2], acc[r][3]);
            }
        }
    }
}

extern "C" void kernel_launch(void* const* d_in, const int* in_sizes, int n_in,
                              void* d_out, int out_size, void* d_ws, size_t ws_size,
                              hipStream_t stream) {
    const float* ev = (const float*)d_in[0];
    float* out = (float*)d_out;

    const int grid = BB * (NN / ROWS);   // 512 blocks, 256 threads
    ExpandEvecs_75780402970966_kernel<<<grid, 256, 0, stream>>>(ev, out);
}